// Round 11
// baseline (2224.167 us; speedup 1.0000x reference)
//
#include <hip/hip_runtime.h>
#include <hip/hip_bf16.h>
#include <hip/hip_fp16.h>

// Problem constants (Slot_Attention reference) — fp32 I/O per the reference.
#define B_    8
#define N_    1024
#define M_    4096
#define C_    512
#define KNN_  16
#define ITERS_ 3

typedef short short8 __attribute__((ext_vector_type(8)));   // 8 bf16 (4 VGPRs)
typedef float float4v __attribute__((ext_vector_type(4)));  // MFMA accum

// async global->LDS, 16 bytes per lane (literal size required)
__device__ __forceinline__ void gl16(const __hip_bfloat16* g, short* l) {
    __builtin_amdgcn_global_load_lds(
        (const __attribute__((address_space(1))) unsigned int*)g,
        (__attribute__((address_space(3))) unsigned int*)l, 16, 0, 0);
}

// ---------------------------------------------------------------------------
// converters
// ---------------------------------------------------------------------------
__global__ void f32_to_f64_k(const float* __restrict__ in,
                             double* __restrict__ out, int n) {
    int i = blockIdx.x * blockDim.x + threadIdx.x;
    int stride = gridDim.x * blockDim.x;
    for (; i < n; i += stride) out[i] = (double)in[i];
}

__global__ void f64_to_f32_k(const double* __restrict__ in,
                             float* __restrict__ out, int n) {
    int i = blockIdx.x * blockDim.x + threadIdx.x;
    int stride = gridDim.x * blockDim.x;
    for (; i < n; i += stride) out[i] = (float)in[i];
}

// ---------------------------------------------------------------------------
// fused fp64 row-norm + bf16 hi/lo split of the normalized row.
// One wave per row; sum order identical across rounds -> inv-norms bit-exact.
// ---------------------------------------------------------------------------
__global__ void norm_split_ref_k(const float* __restrict__ ref,
                                 double* __restrict__ invn, double* __restrict__ rn,
                                 __hip_bfloat16* __restrict__ hi, __hip_bfloat16* __restrict__ lo) {
    const int row = blockIdx.x, lane = threadIdx.x;   // 64 threads
    const float* p = ref + (size_t)row * C_;
    double s = 0.0;
    for (int i = lane; i < C_; i += 64) { double v = (double)p[i]; s += v * v; }
    for (int o = 32; o > 0; o >>= 1) s += __shfl_down(s, o);
    s = __shfl(s, 0);
    if (lane == 0) { invn[row] = 1.0 / sqrt(s); rn[row] = sqrt(s); }
    const double inv = 1.0 / sqrt(s);
    for (int i = lane; i < C_; i += 64) {
        float x = (float)((double)p[i] * inv);
        __hip_bfloat16 h = __float2bfloat16(x);
        hi[(size_t)row * C_ + i] = h;
        lo[(size_t)row * C_ + i] = __float2bfloat16(x - __bfloat162float(h));
    }
}

__global__ void norm_split_slots_k(const double* __restrict__ slots,
                                   double* __restrict__ invn,
                                   __hip_bfloat16* __restrict__ hi, __hip_bfloat16* __restrict__ lo) {
    const int row = blockIdx.x, lane = threadIdx.x;   // 64 threads
    const double* p = slots + (size_t)row * C_;
    double s = 0.0;
    for (int i = lane; i < C_; i += 64) { double v = p[i]; s += v * v; }
    for (int o = 32; o > 0; o >>= 1) s += __shfl_down(s, o);
    s = __shfl(s, 0);
    if (lane == 0) invn[row] = 1.0 / sqrt(s);
    const double inv = 1.0 / sqrt(s);
    for (int i = lane; i < C_; i += 64) {
        float x = (float)(p[i] * inv);
        __hip_bfloat16 h = __float2bfloat16(x);
        hi[(size_t)row * C_ + i] = h;
        lo[(size_t)row * C_ + i] = __float2bfloat16(x - __bfloat162float(h));
    }
}

// ---------------------------------------------------------------------------
// transpose-split of Wk and Wv: Wt[c][k] = bf16split(W[k][c]); tiny.
// ---------------------------------------------------------------------------
__global__ void split_w_k(const float* __restrict__ Wk, const float* __restrict__ Wv,
                          __hip_bfloat16* __restrict__ kh, __hip_bfloat16* __restrict__ kl,
                          __hip_bfloat16* __restrict__ vh, __hip_bfloat16* __restrict__ vl) {
    int i = blockIdx.x * blockDim.x + threadIdx.x;
    int stride = gridDim.x * blockDim.x;
    for (; i < C_ * C_; i += stride) {
        int k = i >> 9, c = i & (C_ - 1);
        int o = c * C_ + k;
        float x = Wk[i];
        __hip_bfloat16 h = __float2bfloat16(x);
        kh[o] = h; kl[o] = __float2bfloat16(x - __bfloat162float(h));
        x = Wv[i];
        h = __float2bfloat16(x);
        vh[o] = h; vl[o] = __float2bfloat16(x - __bfloat162float(h));
    }
}

// ---------------------------------------------------------------------------
// split-bf16 MFMA NT GEMM: C[I x J] = (Ah+Al) . (Bh+Bl)^T (both row-major
// over K=512). 128x128 tile, 4 waves (2x2), BK=32, global_load_lds staging,
// linear LDS [128][32].
//   FULL=true : 3 MFMAs, fp32 output (opt. per-A-row fp64 scale) —
//               trajectory-critical GEMMs (Kb/Vb).
//   FULL=false: 2 MFMAs ((ah+al).bh), Bl never staged, FP16 output — corr
//     only. corr feeds candidate NOMINATION (radix + exact fp64 re-rank);
//     2-MFMA error ~2e-4 + fp16 round ~2.4e-4 << rank16-rank40 gap ~7e-3.
// z-batched via strides (strideCz in OUTPUT elements).
// ---------------------------------------------------------------------------
template <bool FULL>
__global__ __launch_bounds__(256) void mfma_nt_k(const __hip_bfloat16* __restrict__ Ahi,
                                                 const __hip_bfloat16* __restrict__ Alo,
                                                 size_t strideAz,
                                                 const __hip_bfloat16* __restrict__ Bhi,
                                                 const __hip_bfloat16* __restrict__ Blo,
                                                 size_t strideBz,
                                                 float* __restrict__ C, size_t strideCz,
                                                 int J,
                                                 const double* __restrict__ rowScale) {
    __shared__ short AhS[128 * 32];
    __shared__ short AlS[128 * 32];
    __shared__ short BhS[128 * 32];
    __shared__ short BlS[FULL ? 128 * 32 : 64];
    const int z = blockIdx.z;
    const __hip_bfloat16* Ah = Ahi + (size_t)z * strideAz;
    const __hip_bfloat16* Al = Alo + (size_t)z * strideAz;
    const __hip_bfloat16* Bh = Bhi + (size_t)z * strideBz;
    const __hip_bfloat16* Bl = Blo + (size_t)z * strideBz;

    const int t = threadIdx.x;
    const int lane = t & 63, wid = t >> 6;
    const int quad = lane >> 4, l15 = lane & 15;
    const int wy = wid >> 1, wx = wid & 1;          // 2x2 wave grid
    const int row0 = blockIdx.y * 128;              // A rows
    const int col0 = blockIdx.x * 128;              // B rows (C cols)

    const int srow = wid * 16 + (lane >> 2);        // 0..63
    const int scol = (lane & 3) * 8;                // shorts
    const size_t aoff0 = (size_t)(row0 + srow) * C_ + scol;
    const size_t aoff1 = (size_t)(row0 + 64 + srow) * C_ + scol;
    const size_t boff0 = (size_t)(col0 + srow) * C_ + scol;
    const size_t boff1 = (size_t)(col0 + 64 + srow) * C_ + scol;
    const int lds0 = srow * 32 + scol;
    const int lds1 = (64 + srow) * 32 + scol;

    float4v acc[4][4];
#pragma unroll
    for (int i = 0; i < 4; ++i)
#pragma unroll
        for (int j = 0; j < 4; ++j) acc[i][j] = (float4v){0.f, 0.f, 0.f, 0.f};

    for (int k0 = 0; k0 < C_; k0 += 32) {
        __syncthreads();
        gl16(Ah + aoff0 + k0, &AhS[lds0]);
        gl16(Ah + aoff1 + k0, &AhS[lds1]);
        gl16(Al + aoff0 + k0, &AlS[lds0]);
        gl16(Al + aoff1 + k0, &AlS[lds1]);
        gl16(Bh + boff0 + k0, &BhS[lds0]);
        gl16(Bh + boff1 + k0, &BhS[lds1]);
        if (FULL) {
            gl16(Bl + boff0 + k0, &BlS[lds0]);
            gl16(Bl + boff1 + k0, &BlS[lds1]);
        }
        __syncthreads();

        short8 ah[4], al[4], bh[4], bl[4];
#pragma unroll
        for (int rt = 0; rt < 4; ++rt) {
            int r = (wy * 64 + rt * 16 + l15) * 32 + quad * 8;
            ah[rt] = *(const short8*)&AhS[r];
            al[rt] = *(const short8*)&AlS[r];
        }
#pragma unroll
        for (int ct = 0; ct < 4; ++ct) {
            int r = (wx * 64 + ct * 16 + l15) * 32 + quad * 8;
            bh[ct] = *(const short8*)&BhS[r];
            if (FULL) bl[ct] = *(const short8*)&BlS[r];
        }
#pragma unroll
        for (int rt = 0; rt < 4; ++rt)
#pragma unroll
            for (int ct = 0; ct < 4; ++ct) {
                acc[rt][ct] = __builtin_amdgcn_mfma_f32_16x16x32_bf16(ah[rt], bh[ct], acc[rt][ct], 0, 0, 0);
                if (FULL)
                    acc[rt][ct] = __builtin_amdgcn_mfma_f32_16x16x32_bf16(ah[rt], bl[ct], acc[rt][ct], 0, 0, 0);
                acc[rt][ct] = __builtin_amdgcn_mfma_f32_16x16x32_bf16(al[rt], bh[ct], acc[rt][ct], 0, 0, 0);
            }
    }

    // epilogue: D[m][n]: n = lane&15, m = quad*4 + reg
    float* Czf = C + (size_t)z * strideCz;
    __half* Czh = (__half*)C + (size_t)z * strideCz;
#pragma unroll
    for (int rt = 0; rt < 4; ++rt) {
        int mbase = row0 + wy * 64 + rt * 16 + quad * 4;
#pragma unroll
        for (int ct = 0; ct < 4; ++ct) {
            int n = col0 + wx * 64 + ct * 16 + l15;
#pragma unroll
            for (int reg = 0; reg < 4; ++reg) {
                float v = acc[rt][ct][reg];
                size_t o = (size_t)(mbase + reg) * J + n;
                if (FULL) {
                    if (rowScale) v *= (float)rowScale[mbase + reg];
                    Czf[o] = v;
                } else {
                    Czh[o] = __float2half(v);
                }
            }
        }
    }
}

// ---------------------------------------------------------------------------
// fused candidate-select (fp16 corr, radix) + exact fp64 re-rank.
// One block per global slot row (B*N blocks). fp16 corr halves the stream
// AND tightens radix bins (6 mantissa bits vs fp32-key's 3) -> fewer
// boundary ties -> smaller candidate set -> less gather traffic.
// XCD swizzle + conflict-free chunk scan from round 10. Exact fp64 re-rank
// and comparator unchanged -> same top-16.
// ---------------------------------------------------------------------------
__global__ __launch_bounds__(256, 6) void select_rerank_k(const __half* __restrict__ corr,
                                                          const double* __restrict__ slots,
                                                          const float* __restrict__ ref,
                                                          const double* __restrict__ inv_ns,
                                                          const double* __restrict__ inv_nr,
                                                          int* __restrict__ idx) {
    __shared__ unsigned hist[4096];     // 16 KB; dead after threshold -> reused
    __shared__ unsigned chunk[256];
    __shared__ double srow[C_];
    __shared__ unsigned thrBin;
    __shared__ int cnt;

    int* candIdx = (int*)hist;                  // hist[0..255]   (1 KB)
    double* candV = (double*)&hist[256];        // hist[256..767] (2 KB, 8B-aligned)

    // XCD-aware remap: batch (row>>10) == bid&7 == XCD id (round-robin dispatch)
    const int row = ((blockIdx.x & 7) << 10) | (blockIdx.x >> 3);
    const int t = threadIdx.x;
    const int bat = row >> 10;                       // N_=1024
    const __half* crow = corr + (size_t)row * M_;
    const float* refb = ref + (size_t)bat * M_ * C_;
    const double* invB = inv_nr + (size_t)bat * M_;

    for (int i = t; i < 4096; i += 256) hist[i] = 0;
    {
        double ia = inv_ns[row];
        for (int i = t; i < C_; i += 256) srow[i] = slots[(size_t)row * C_ + i] * ia;
    }
    if (t == 0) cnt = 0;
    __syncthreads();

    // single streaming pass: 2x 16B loads = 16 halves/thread.
    // element index: j<8 -> 8t+j ; j>=8 -> 2048 + 8t + (j-8).
    uint4 cu0 = *(const uint4*)(crow + 8 * t);
    uint4 cu1 = *(const uint4*)(crow + 2048 + 8 * t);
    const unsigned* cw0 = (const unsigned*)&cu0;
    const unsigned* cw1 = (const unsigned*)&cu1;
    unsigned uv[16];
#pragma unroll
    for (int wd = 0; wd < 4; ++wd) {
        unsigned w0 = cw0[wd], w1 = cw1[wd], h;
        h = w0 & 0xFFFFu; uv[2 * wd]     = (h & 0x8000u) ? (~h & 0xFFFFu) : (h | 0x8000u);
        h = w0 >> 16;     uv[2 * wd + 1] = (h & 0x8000u) ? (~h & 0xFFFFu) : (h | 0x8000u);
        h = w1 & 0xFFFFu; uv[8 + 2 * wd]     = (h & 0x8000u) ? (~h & 0xFFFFu) : (h | 0x8000u);
        h = w1 >> 16;     uv[8 + 2 * wd + 1] = (h & 0x8000u) ? (~h & 0xFFFFu) : (h | 0x8000u);
    }
    unsigned umax = uv[0];
#pragma unroll
    for (int j = 1; j < 16; ++j) umax = uv[j] > umax ? uv[j] : umax;
    atomicAdd(&hist[umax >> 4], 1u);    // 12-bit key: sign+5exp+6mant
    __syncthreads();

    // per-chunk totals, lane-rotated reads (conflict-free); order-independent.
    unsigned mysum;
    {
        const int base = t * 16, rot = t & 15;
        unsigned s = 0;
#pragma unroll
        for (int j = 0; j < 16; ++j) s += hist[base + ((j + rot) & 15)];
        mysum = s;
        chunk[t] = s;
    }
    __syncthreads();
    // exclusive suffix sums over the 256 chunk totals: wave 0, 4 chunks/lane.
    if (t < 64) {
        unsigned v0 = chunk[t * 4 + 0], v1 = chunk[t * 4 + 1];
        unsigned v2 = chunk[t * 4 + 2], v3 = chunk[t * 4 + 3];
        unsigned tot = v0 + v1 + v2 + v3;
        unsigned incl = tot;
#pragma unroll
        for (int off = 1; off < 64; off <<= 1) {
            unsigned o = __shfl_down(incl, off);
            if (t + off < 64) incl += o;
        }
        unsigned excl = incl - tot;
        chunk[t * 4 + 3] = excl;
        chunk[t * 4 + 2] = excl + v3;
        chunk[t * 4 + 1] = excl + v3 + v2;
        chunk[t * 4 + 0] = excl + v3 + v2 + v1;
    }
    __syncthreads();
    // only the single crossing thread walks its 16 bins (no wave conflicts)
    {
        unsigned above = chunk[t];
        if (above < 33u && above + mysum >= 33u) {
            unsigned prev = above;
            for (int b = t * 16 + 15; b >= t * 16; --b) {
                unsigned cur = prev + hist[b];
                if (cur >= 33u && prev < 33u) thrBin = (unsigned)b;
                prev = cur;
            }
        }
    }
    __syncthreads();       // all hist/chunk reads complete; hist reusable below

    const unsigned T = thrBin;
#pragma unroll
    for (int j = 0; j < 16; ++j) {
        if ((uv[j] >> 4) >= T) {
            int p = atomicAdd(&cnt, 1);
            if (p < 256) candIdx[p] = (j < 8) ? (8 * t + j) : (2048 + 8 * t + (j - 8));
        }
    }
    __syncthreads();
    const int nc = cnt < 256 ? cnt : 256;

    // exact fp64 re-rank: per-candidate k-order and reduce order unchanged;
    // four candidates in flight per wave; srow cached in registers.
    {
        const int w = t >> 6, l = t & 63;
        double sreg[8];
#pragma unroll
        for (int k = 0; k < 8; ++k) sreg[k] = srow[l + 64 * k];
        for (int cj = w; cj < nc; cj += 16) {
            int cc[4]; bool has[4]; const float* rp[4]; double ib[4];
#pragma unroll
            for (int q = 0; q < 4; ++q) {
                cc[q] = cj + 4 * q;
                has[q] = cc[q] < nc;
                int col = has[q] ? candIdx[cc[q]] : candIdx[cj];
                rp[q] = refb + (size_t)col * C_;
                ib[q] = has[q] ? invB[col] : 0.0;
            }
            double s[4] = {0.0, 0.0, 0.0, 0.0};
#pragma unroll
            for (int k = 0; k < 8; ++k) {
#pragma unroll
                for (int q = 0; q < 4; ++q)
                    s[q] += sreg[k] * ((double)rp[q][l + 64 * k] * ib[q]);
            }
#pragma unroll
            for (int o = 32; o > 0; o >>= 1) {
#pragma unroll
                for (int q = 0; q < 4; ++q) s[q] += __shfl_down(s[q], o);
            }
            if (l == 0) {
#pragma unroll
                for (int q = 0; q < 4; ++q)
                    if (has[q]) candV[cc[q]] = s[q];
            }
        }
    }
    __syncthreads();

    // single-wave register-resident top-16: 4 candidates/lane, 6-step
    // shfl_xor argmax per round, zero barriers.
    if (t < 64) {
        double v[4]; int g[4];
#pragma unroll
        for (int r = 0; r < 4; ++r) {
            int p = t + 64 * r;
            bool ok = p < nc;
            v[r] = ok ? candV[p] : -1e300;
            g[r] = ok ? candIdx[p] : 0x7fffffff;
        }
        int* orow = idx + (size_t)row * KNN_;
        for (int r = 0; r < KNN_; ++r) {
            double bv = v[0]; int bg = g[0];
#pragma unroll
            for (int q = 1; q < 4; ++q)
                if (v[q] > bv || (v[q] == bv && g[q] < bg)) { bv = v[q]; bg = g[q]; }
#pragma unroll
            for (int off = 32; off > 0; off >>= 1) {
                double ov = __shfl_xor(bv, off);
                int og = __shfl_xor(bg, off);
                if (ov > bv || (ov == bv && og < bg)) { bv = ov; bg = og; }
            }
            if (t == 0) orow[r] = bg;
#pragma unroll
            for (int q = 0; q < 4; ++q)
                if (g[q] == bg) v[q] = -1e300;
        }
    }
}

// ---------------------------------------------------------------------------
// fp64 NN GEMM: out(rows x 512) = A(rows x 512) @ W(512x512 fp32) [+ res]
// 128x64 tile, 256 threads, 8x4 microtile, BK=16. Per-element k-order
// identical to the verified rounds -> bit-exact trajectory. fp64 stays:
// slots trajectory feeds the discrete KNN selection (round-5 lesson; the
// np reference is selection-exact at this noise level).
// ---------------------------------------------------------------------------
template <bool RES>
__global__ __launch_bounds__(256) void gemm_f64_k(const double* __restrict__ A,
                                                  const float* __restrict__ W,
                                                  const double* __restrict__ res,
                                                  double* __restrict__ out) {
    __shared__ double As[16][130];
    __shared__ double Bs[16][66];
    const int tx = threadIdx.x, ty = threadIdx.y;   // 16 x 16
    const int t = ty * 16 + tx;
    const int lk = t & 15, lr = t >> 4;
    const int wc = t & 63, wk = t >> 6;
    const int row0 = blockIdx.y * 128, col0 = blockIdx.x * 64;
    double acc[8][4] = {};
    for (int k0 = 0; k0 < C_; k0 += 16) {
#pragma unroll
        for (int p = 0; p < 8; ++p) {
            int r = lr + 16 * p;
            As[lk][r] = A[(size_t)(row0 + r) * C_ + k0 + lk];
        }
#pragma unroll
        for (int p = 0; p < 4; ++p)
            Bs[wk + 4 * p][wc] = (double)W[(size_t)(k0 + wk + 4 * p) * C_ + col0 + wc];
        __syncthreads();
#pragma unroll
        for (int kk = 0; kk < 16; ++kk) {
            double a[8], b[4];
#pragma unroll
            for (int i = 0; i < 8; ++i) a[i] = As[kk][ty * 8 + i];
#pragma unroll
            for (int j = 0; j < 4; ++j) b[j] = Bs[kk][tx * 4 + j];
#pragma unroll
            for (int i = 0; i < 8; ++i)
#pragma unroll
                for (int j = 0; j < 4; ++j) acc[i][j] += a[i] * b[j];
        }
        __syncthreads();
    }
#pragma unroll
    for (int i = 0; i < 8; ++i) {
        size_t r = row0 + ty * 8 + i;
#pragma unroll
        for (int j = 0; j < 4; ++j) {
            size_t o = r * C_ + col0 + tx * 4 + j;
            double v = acc[i][j];
            if (RES) v += res[o];
            out[o] = v;
        }
    }
}

// ---------------------------------------------------------------------------
// per-row 16-way cross attention, IN-PLACE on q, batched over B*N rows.
// XCD swizzle (same remap as select) for Kb/Vb gather L2 locality.
// Per-wave shfl logit reduce + 16-lane shfl softmax (round-4, passed).
// ---------------------------------------------------------------------------
__global__ __launch_bounds__(256) void attn_k(double* qo,
                                              const float* __restrict__ Kb,
                                              const float* __restrict__ Vb,
                                              const int* __restrict__ idx) {
    const int row = ((blockIdx.x & 7) << 10) | (blockIdx.x >> 3);   // batch->XCD
    const int bat = row >> 10;
    const int t = threadIdx.x;
    const int lane = t & 63, w = t >> 6;
    __shared__ int sidx[KNN_];
    __shared__ double wred[4][KNN_];
    __shared__ double sw[KNN_];
    if (t < KNN_) sidx[t] = idx[(size_t)row * KNN_ + t];
    __syncthreads();
    double q0 = qo[(size_t)row * C_ + t];
    double q1 = qo[(size_t)row * C_ + t + 256];
    double p[KNN_];
#pragma unroll
    for (int j = 0; j < KNN_; ++j) {
        const float* kr = Kb + ((size_t)bat * M_ + sidx[j]) * C_;
        p[j] = q0 * (double)kr[t] + q1 * (double)kr[t + 256];
    }
#pragma unroll
    for (int j = 0; j < KNN_; ++j) {
        double s = p[j];
#pragma unroll
        for (int o = 32; o > 0; o >>= 1) s += __shfl_down(s, o);
        if (lane == 0) wred[w][j] = s;
    }
    __syncthreads();
    if (t < KNN_) {
        const double scale = 1.0 / sqrt((double)C_);
        double l = (wred[0][t] + wred[1][t] + wred[2][t] + wred[3][t]) * scale;
        double mx = l;
#pragma unroll
        for (int o = 8; o > 0; o >>= 1) {
            double om = __shfl_xor(mx, o, 16);
            mx = om > mx ? om : mx;
        }
        double e = exp(l - mx);
        double ssum = e;
#pragma unroll
        for (int o = 8; o > 0; o >>= 1) ssum += __shfl_xor(ssum, o, 16);
        sw[t] = e * (1.0 / ssum);
    }
    __syncthreads();
    double o0 = 0.0, o1 = 0.0;
#pragma unroll
    for (int j = 0; j < KNN_; ++j) {
        const float* vr = Vb + ((size_t)bat * M_ + sidx[j]) * C_;
        double wgt = sw[j];
        o0 += wgt * (double)vr[t];
        o1 += wgt * (double)vr[t + 256];
    }
    qo[(size_t)row * C_ + t] = o0;
    qo[(size_t)row * C_ + t + 256] = o1;
}

// ---------------------------------------------------------------------------
extern "C" void kernel_launch(void* const* d_in, const int* in_sizes, int n_in,
                              void* d_out, int out_size, void* d_ws, size_t ws_size,
                              hipStream_t stream) {
    const float* slots_in = (const float*)d_in[0];
    const float* reflist  = (const float*)d_in[1];
    const float* Wq = (const float*)d_in[2];
    const float* Wk = (const float*)d_in[3];
    const float* Wv = (const float*)d_in[4];
    const float* Wo = (const float*)d_in[5];
    // reference uses only the LAST ref in ref_pt_list
    const float* ref = reflist + ((size_t)in_sizes[1] - (size_t)B_ * M_ * C_);
    float* out = (float*)d_out;

    const size_t NR = (size_t)B_ * N_;   // 8192 slot rows
    const size_t MR = (size_t)B_ * M_;   // 32768 ref rows

    // workspace carve — all-batch layout, ~322 MB of 512 MiB
    char* w = (char*)d_ws;
    double* slots_d = (double*)w;             w += NR * C_ * 8;            //  33.5 MB
    __half* corrh   = (__half*)w;             w += NR * M_ * 2;            //  67.1 MB (fp16)
    float*  Kb      = (float*)w;              w += MR * C_ * 4;            //  67.1 MB
    float*  Vb      = (float*)w;              w += MR * C_ * 4;            //  67.1 MB
    __hip_bfloat16* Bhi = (__hip_bfloat16*)w; w += MR * C_ * 2;            //  33.5 MB
    __hip_bfloat16* Blo = (__hip_bfloat16*)w; w += MR * C_ * 2;            //  33.5 MB
    __hip_bfloat16* Ahi = (__hip_bfloat16*)w; w += NR * C_ * 2;            //   8.4 MB
    __hip_bfloat16* Alo = (__hip_bfloat16*)w; w += NR * C_ * 2;            //   8.4 MB
    __hip_bfloat16* Wkh = (__hip_bfloat16*)w; w += (size_t)C_ * C_ * 2;
    __hip_bfloat16* Wkl = (__hip_bfloat16*)w; w += (size_t)C_ * C_ * 2;
    __hip_bfloat16* Wvh = (__hip_bfloat16*)w; w += (size_t)C_ * C_ * 2;
    __hip_bfloat16* Wvl = (__hip_bfloat16*)w; w += (size_t)C_ * C_ * 2;
    double* inv_ns  = (double*)w;             w += NR * 8;
    double* inv_nr  = (double*)w;             w += MR * 8;
    double* rn      = (double*)w;             w += MR * 8;
    int*    idxb    = (int*)w;                w += NR * KNN_ * 4;
    double* qbuf    = (double*)corrh;  // corr dead after select; fp64 q = 33.5 MB

    // ---- setup (once) ----
    f32_to_f64_k<<<4096, 256, 0, stream>>>(slots_in, slots_d, (int)(NR * C_));
    norm_split_ref_k<<<(int)MR, 64, 0, stream>>>(ref, inv_nr, rn, Bhi, Blo);
    split_w_k<<<512, 256, 0, stream>>>(Wk, Wv, Wkh, Wkl, Wvh, Wvl);
    // Kb = rn .* (ref_n @ Wk), Vb analogous — full 3-MFMA split (trajectory-
    // critical precision, round-5 lesson), rows = 32768
    mfma_nt_k<true><<<dim3(C_ / 128, MR / 128, 1), 256, 0, stream>>>(
        Bhi, Blo, 0, Wkh, Wkl, 0, Kb, 0, C_, rn);
    mfma_nt_k<true><<<dim3(C_ / 128, MR / 128, 1), 256, 0, stream>>>(
        Bhi, Blo, 0, Wvh, Wvl, 0, Vb, 0, C_, rn);

    for (int it = 0; it < ITERS_; ++it) {
        norm_split_slots_k<<<(int)NR, 64, 0, stream>>>(slots_d, inv_ns, Ahi, Alo);
        // corr (fp16 out, 2-MFMA split — nomination-only precision), z = batch
        mfma_nt_k<false><<<dim3(M_ / 128, N_ / 128, B_), 256, 0, stream>>>(
            Ahi, Alo, (size_t)N_ * C_, Bhi, Blo, (size_t)M_ * C_,
            (float*)corrh, (size_t)N_ * M_, M_, nullptr);
        select_rerank_k<<<(int)NR, 256, 0, stream>>>(corrh, slots_d, ref, inv_ns, inv_nr, idxb);
        // q = slots @ Wq (fp64, into corr-aliased qbuf)
        gemm_f64_k<false><<<dim3(C_ / 64, NR / 128), dim3(16, 16), 0, stream>>>(
            slots_d, Wq, (const double*)nullptr, qbuf);
        attn_k<<<(int)NR, 256, 0, stream>>>(qbuf, Kb, Vb, idxb);
        // slots += attnout @ Wo (fp64)
        gemm_f64_k<true><<<dim3(C_ / 64, NR / 128), dim3(16, 16), 0, stream>>>(
            qbuf, Wo, slots_d, slots_d);
    }

    f64_to_f32_k<<<4096, 256, 0, stream>>>(slots_d, out, (int)(NR * C_));
}

// Round 12
// 2064.334 us; speedup vs baseline: 1.0774x; 1.0774x over previous
//
#include <hip/hip_runtime.h>
#include <hip/hip_bf16.h>

// Problem constants (Slot_Attention reference) — fp32 I/O per the reference.
#define B_    8
#define N_    1024
#define M_    4096
#define C_    512
#define KNN_  16
#define ITERS_ 3

typedef short short8 __attribute__((ext_vector_type(8)));   // 8 bf16 (4 VGPRs)
typedef float float4v __attribute__((ext_vector_type(4)));  // MFMA accum

// async global->LDS, 16 bytes per lane (literal size required)
__device__ __forceinline__ void gl16(const __hip_bfloat16* g, short* l) {
    __builtin_amdgcn_global_load_lds(
        (const __attribute__((address_space(1))) unsigned int*)g,
        (__attribute__((address_space(3))) unsigned int*)l, 16, 0, 0);
}

// ---------------------------------------------------------------------------
// converters
// ---------------------------------------------------------------------------
__global__ void f32_to_f64_k(const float* __restrict__ in,
                             double* __restrict__ out, int n) {
    int i = blockIdx.x * blockDim.x + threadIdx.x;
    int stride = gridDim.x * blockDim.x;
    for (; i < n; i += stride) out[i] = (double)in[i];
}

__global__ void f64_to_f32_k(const double* __restrict__ in,
                             float* __restrict__ out, int n) {
    int i = blockIdx.x * blockDim.x + threadIdx.x;
    int stride = gridDim.x * blockDim.x;
    for (; i < n; i += stride) out[i] = (float)in[i];
}

// ---------------------------------------------------------------------------
// fused fp64 row-norm + bf16 hi/lo split of the normalized row.
// One wave per row; sum order identical across rounds -> inv-norms bit-exact.
// ---------------------------------------------------------------------------
__global__ void norm_split_ref_k(const float* __restrict__ ref,
                                 double* __restrict__ invn, double* __restrict__ rn,
                                 __hip_bfloat16* __restrict__ hi, __hip_bfloat16* __restrict__ lo) {
    const int row = blockIdx.x, lane = threadIdx.x;   // 64 threads
    const float* p = ref + (size_t)row * C_;
    double s = 0.0;
    for (int i = lane; i < C_; i += 64) { double v = (double)p[i]; s += v * v; }
    for (int o = 32; o > 0; o >>= 1) s += __shfl_down(s, o);
    s = __shfl(s, 0);
    if (lane == 0) { invn[row] = 1.0 / sqrt(s); rn[row] = sqrt(s); }
    const double inv = 1.0 / sqrt(s);
    for (int i = lane; i < C_; i += 64) {
        float x = (float)((double)p[i] * inv);
        __hip_bfloat16 h = __float2bfloat16(x);
        hi[(size_t)row * C_ + i] = h;
        lo[(size_t)row * C_ + i] = __float2bfloat16(x - __bfloat162float(h));
    }
}

__global__ void norm_split_slots_k(const double* __restrict__ slots,
                                   double* __restrict__ invn,
                                   __hip_bfloat16* __restrict__ hi, __hip_bfloat16* __restrict__ lo) {
    const int row = blockIdx.x, lane = threadIdx.x;   // 64 threads
    const double* p = slots + (size_t)row * C_;
    double s = 0.0;
    for (int i = lane; i < C_; i += 64) { double v = p[i]; s += v * v; }
    for (int o = 32; o > 0; o >>= 1) s += __shfl_down(s, o);
    s = __shfl(s, 0);
    if (lane == 0) invn[row] = 1.0 / sqrt(s);
    const double inv = 1.0 / sqrt(s);
    for (int i = lane; i < C_; i += 64) {
        float x = (float)(p[i] * inv);
        __hip_bfloat16 h = __float2bfloat16(x);
        hi[(size_t)row * C_ + i] = h;
        lo[(size_t)row * C_ + i] = __float2bfloat16(x - __bfloat162float(h));
    }
}

// ---------------------------------------------------------------------------
// transpose-split of Wk and Wv: Wt[c][k] = bf16split(W[k][c]); tiny.
// ---------------------------------------------------------------------------
__global__ void split_w_k(const float* __restrict__ Wk, const float* __restrict__ Wv,
                          __hip_bfloat16* __restrict__ kh, __hip_bfloat16* __restrict__ kl,
                          __hip_bfloat16* __restrict__ vh, __hip_bfloat16* __restrict__ vl) {
    int i = blockIdx.x * blockDim.x + threadIdx.x;
    int stride = gridDim.x * blockDim.x;
    for (; i < C_ * C_; i += stride) {
        int k = i >> 9, c = i & (C_ - 1);
        int o = c * C_ + k;
        float x = Wk[i];
        __hip_bfloat16 h = __float2bfloat16(x);
        kh[o] = h; kl[o] = __float2bfloat16(x - __bfloat162float(h));
        x = Wv[i];
        h = __float2bfloat16(x);
        vh[o] = h; vl[o] = __float2bfloat16(x - __bfloat162float(h));
    }
}

// ---------------------------------------------------------------------------
// split-bf16 MFMA NT GEMM: C[I x J] fp32 = (Ah+Al) . (Bh+Bl)^T (both row-major
// over K=512). 128x128 tile, 4 waves (2x2), BK=32, global_load_lds staging,
// linear LDS [128][32].
//   FULL=true : 3 MFMAs (ah.bh + ah.bl + al.bh) — trajectory-critical GEMMs.
//   FULL=false: 2 MFMAs ((ah+al).bh), Bl never staged — corr only. corr
//     feeds candidate NOMINATION (radix + exact fp64 re-rank);
//     dropped-term error ~2e-4 << rank16-rank32 corr gap ~7e-3.
//   (fp16 corr output tried in r11: select regressed +76us/dispatch — fp32
//    corr is the verified-fast configuration. Do not retry without a
//    mechanism explanation.)
// z-batched via strides; optional per-A-row fp64 scale in the epilogue.
// ---------------------------------------------------------------------------
template <bool FULL>
__global__ __launch_bounds__(256) void mfma_nt_k(const __hip_bfloat16* __restrict__ Ahi,
                                                 const __hip_bfloat16* __restrict__ Alo,
                                                 size_t strideAz,
                                                 const __hip_bfloat16* __restrict__ Bhi,
                                                 const __hip_bfloat16* __restrict__ Blo,
                                                 size_t strideBz,
                                                 float* __restrict__ C, size_t strideCz,
                                                 int J,
                                                 const double* __restrict__ rowScale) {
    __shared__ short AhS[128 * 32];
    __shared__ short AlS[128 * 32];
    __shared__ short BhS[128 * 32];
    __shared__ short BlS[FULL ? 128 * 32 : 64];
    const int z = blockIdx.z;
    const __hip_bfloat16* Ah = Ahi + (size_t)z * strideAz;
    const __hip_bfloat16* Al = Alo + (size_t)z * strideAz;
    const __hip_bfloat16* Bh = Bhi + (size_t)z * strideBz;
    const __hip_bfloat16* Bl = Blo + (size_t)z * strideBz;
    float* Cz = C + (size_t)z * strideCz;

    const int t = threadIdx.x;
    const int lane = t & 63, wid = t >> 6;
    const int quad = lane >> 4, l15 = lane & 15;
    const int wy = wid >> 1, wx = wid & 1;          // 2x2 wave grid
    const int row0 = blockIdx.y * 128;              // A rows
    const int col0 = blockIdx.x * 128;              // B rows (C cols)

    const int srow = wid * 16 + (lane >> 2);        // 0..63
    const int scol = (lane & 3) * 8;                // shorts
    const size_t aoff0 = (size_t)(row0 + srow) * C_ + scol;
    const size_t aoff1 = (size_t)(row0 + 64 + srow) * C_ + scol;
    const size_t boff0 = (size_t)(col0 + srow) * C_ + scol;
    const size_t boff1 = (size_t)(col0 + 64 + srow) * C_ + scol;
    const int lds0 = srow * 32 + scol;
    const int lds1 = (64 + srow) * 32 + scol;

    float4v acc[4][4];
#pragma unroll
    for (int i = 0; i < 4; ++i)
#pragma unroll
        for (int j = 0; j < 4; ++j) acc[i][j] = (float4v){0.f, 0.f, 0.f, 0.f};

    for (int k0 = 0; k0 < C_; k0 += 32) {
        __syncthreads();
        gl16(Ah + aoff0 + k0, &AhS[lds0]);
        gl16(Ah + aoff1 + k0, &AhS[lds1]);
        gl16(Al + aoff0 + k0, &AlS[lds0]);
        gl16(Al + aoff1 + k0, &AlS[lds1]);
        gl16(Bh + boff0 + k0, &BhS[lds0]);
        gl16(Bh + boff1 + k0, &BhS[lds1]);
        if (FULL) {
            gl16(Bl + boff0 + k0, &BlS[lds0]);
            gl16(Bl + boff1 + k0, &BlS[lds1]);
        }
        __syncthreads();

        short8 ah[4], al[4], bh[4], bl[4];
#pragma unroll
        for (int rt = 0; rt < 4; ++rt) {
            int r = (wy * 64 + rt * 16 + l15) * 32 + quad * 8;
            ah[rt] = *(const short8*)&AhS[r];
            al[rt] = *(const short8*)&AlS[r];
        }
#pragma unroll
        for (int ct = 0; ct < 4; ++ct) {
            int r = (wx * 64 + ct * 16 + l15) * 32 + quad * 8;
            bh[ct] = *(const short8*)&BhS[r];
            if (FULL) bl[ct] = *(const short8*)&BlS[r];
        }
#pragma unroll
        for (int rt = 0; rt < 4; ++rt)
#pragma unroll
            for (int ct = 0; ct < 4; ++ct) {
                acc[rt][ct] = __builtin_amdgcn_mfma_f32_16x16x32_bf16(ah[rt], bh[ct], acc[rt][ct], 0, 0, 0);
                if (FULL)
                    acc[rt][ct] = __builtin_amdgcn_mfma_f32_16x16x32_bf16(ah[rt], bl[ct], acc[rt][ct], 0, 0, 0);
                acc[rt][ct] = __builtin_amdgcn_mfma_f32_16x16x32_bf16(al[rt], bh[ct], acc[rt][ct], 0, 0, 0);
            }
    }

    // epilogue: D[m][n]: n = lane&15, m = quad*4 + reg
#pragma unroll
    for (int rt = 0; rt < 4; ++rt) {
        int mbase = row0 + wy * 64 + rt * 16 + quad * 4;
#pragma unroll
        for (int ct = 0; ct < 4; ++ct) {
            int n = col0 + wx * 64 + ct * 16 + l15;
#pragma unroll
            for (int reg = 0; reg < 4; ++reg) {
                float v = acc[rt][ct][reg];
                if (rowScale) v *= (float)rowScale[mbase + reg];
                Cz[(size_t)(mbase + reg) * J + n] = v;
            }
        }
    }
}

// ---------------------------------------------------------------------------
// fused candidate-select (fp32 corr, radix) + exact fp64 re-rank.
// One block per global slot row (B*N blocks). Round-10 structure (verified
// 162us): per-thread-max histogram, conflict-free chunk scan, XCD swizzle.
// This round: corr float4 loads issued at kernel ENTRY (issue-early) so HBM
// latency hides under hist-zero + srow staging. Values/selection identical.
// ---------------------------------------------------------------------------
__global__ __launch_bounds__(256, 6) void select_rerank_k(const float* __restrict__ corr,
                                                          const double* __restrict__ slots,
                                                          const float* __restrict__ ref,
                                                          const double* __restrict__ inv_ns,
                                                          const double* __restrict__ inv_nr,
                                                          int* __restrict__ idx) {
    __shared__ unsigned hist[4096];     // 16 KB; dead after threshold -> reused
    __shared__ unsigned chunk[256];
    __shared__ double srow[C_];
    __shared__ unsigned thrBin;
    __shared__ int cnt;

    int* candIdx = (int*)hist;                  // hist[0..255]   (1 KB)
    double* candV = (double*)&hist[256];        // hist[256..767] (2 KB, 8B-aligned)

    // XCD-aware remap: batch (row>>10) == bid&7 == XCD id (round-robin dispatch)
    const int row = ((blockIdx.x & 7) << 10) | (blockIdx.x >> 3);
    const int t = threadIdx.x;
    const int bat = row >> 10;                       // N_=1024
    const float* crow = corr + (size_t)row * M_;
    const float* refb = ref + (size_t)bat * M_ * C_;
    const double* invB = inv_nr + (size_t)bat * M_;

    // issue corr stream FIRST (latency hides under LDS init + srow staging)
    const float4* crow4 = (const float4*)crow;
    float4 cf[4];
#pragma unroll
    for (int j = 0; j < 4; ++j) cf[j] = crow4[t + 256 * j];

    for (int i = t; i < 4096; i += 256) hist[i] = 0;
    {
        double ia = inv_ns[row];
        for (int i = t; i < C_; i += 256) srow[i] = slots[(size_t)row * C_ + i] * ia;
    }
    if (t == 0) cnt = 0;
    __syncthreads();

    unsigned uv[16];
#pragma unroll
    for (int j = 0; j < 4; ++j) {
#pragma unroll
        for (int e = 0; e < 4; ++e) {
            unsigned u = __float_as_uint(((const float*)&cf[j])[e]);
            u = (u & 0x80000000u) ? ~u : (u | 0x80000000u);
            uv[j * 4 + e] = u;
        }
    }
    unsigned umax = uv[0];
#pragma unroll
    for (int j = 1; j < 16; ++j) umax = uv[j] > umax ? uv[j] : umax;
    atomicAdd(&hist[umax >> 20], 1u);
    __syncthreads();

    // per-chunk totals, lane-rotated reads (conflict-free); order-independent.
    unsigned mysum;
    {
        const int base = t * 16, rot = t & 15;
        unsigned s = 0;
#pragma unroll
        for (int j = 0; j < 16; ++j) s += hist[base + ((j + rot) & 15)];
        mysum = s;
        chunk[t] = s;
    }
    __syncthreads();
    // exclusive suffix sums over the 256 chunk totals: wave 0, 4 chunks/lane.
    if (t < 64) {
        unsigned v0 = chunk[t * 4 + 0], v1 = chunk[t * 4 + 1];
        unsigned v2 = chunk[t * 4 + 2], v3 = chunk[t * 4 + 3];
        unsigned tot = v0 + v1 + v2 + v3;
        unsigned incl = tot;
#pragma unroll
        for (int off = 1; off < 64; off <<= 1) {
            unsigned o = __shfl_down(incl, off);
            if (t + off < 64) incl += o;
        }
        unsigned excl = incl - tot;
        chunk[t * 4 + 3] = excl;
        chunk[t * 4 + 2] = excl + v3;
        chunk[t * 4 + 1] = excl + v3 + v2;
        chunk[t * 4 + 0] = excl + v3 + v2 + v1;
    }
    __syncthreads();
    // only the single crossing thread walks its 16 bins (no wave conflicts)
    {
        unsigned above = chunk[t];
        if (above < 33u && above + mysum >= 33u) {
            unsigned prev = above;
            for (int b = t * 16 + 15; b >= t * 16; --b) {
                unsigned cur = prev + hist[b];
                if (cur >= 33u && prev < 33u) thrBin = (unsigned)b;
                prev = cur;
            }
        }
    }
    __syncthreads();       // all hist/chunk reads complete; hist reusable below

    const unsigned T = thrBin;
#pragma unroll
    for (int j = 0; j < 4; ++j) {
#pragma unroll
        for (int e = 0; e < 4; ++e) {
            if ((uv[j * 4 + e] >> 20) >= T) {
                int p = atomicAdd(&cnt, 1);
                if (p < 256) candIdx[p] = 1024 * j + 4 * t + e;
            }
        }
    }
    __syncthreads();
    const int nc = cnt < 256 ? cnt : 256;

    // exact fp64 re-rank: per-candidate k-order and reduce order unchanged;
    // four candidates in flight per wave; srow cached in registers.
    {
        const int w = t >> 6, l = t & 63;
        double sreg[8];
#pragma unroll
        for (int k = 0; k < 8; ++k) sreg[k] = srow[l + 64 * k];
        for (int cj = w; cj < nc; cj += 16) {
            int cc[4]; bool has[4]; const float* rp[4]; double ib[4];
#pragma unroll
            for (int q = 0; q < 4; ++q) {
                cc[q] = cj + 4 * q;
                has[q] = cc[q] < nc;
                int col = has[q] ? candIdx[cc[q]] : candIdx[cj];
                rp[q] = refb + (size_t)col * C_;
                ib[q] = has[q] ? invB[col] : 0.0;
            }
            double s[4] = {0.0, 0.0, 0.0, 0.0};
#pragma unroll
            for (int k = 0; k < 8; ++k) {
#pragma unroll
                for (int q = 0; q < 4; ++q)
                    s[q] += sreg[k] * ((double)rp[q][l + 64 * k] * ib[q]);
            }
#pragma unroll
            for (int o = 32; o > 0; o >>= 1) {
#pragma unroll
                for (int q = 0; q < 4; ++q) s[q] += __shfl_down(s[q], o);
            }
            if (l == 0) {
#pragma unroll
                for (int q = 0; q < 4; ++q)
                    if (has[q]) candV[cc[q]] = s[q];
            }
        }
    }
    __syncthreads();

    // single-wave register-resident top-16: 4 candidates/lane, 6-step
    // shfl_xor argmax per round, zero barriers.
    if (t < 64) {
        double v[4]; int g[4];
#pragma unroll
        for (int r = 0; r < 4; ++r) {
            int p = t + 64 * r;
            bool ok = p < nc;
            v[r] = ok ? candV[p] : -1e300;
            g[r] = ok ? candIdx[p] : 0x7fffffff;
        }
        int* orow = idx + (size_t)row * KNN_;
        for (int r = 0; r < KNN_; ++r) {
            double bv = v[0]; int bg = g[0];
#pragma unroll
            for (int q = 1; q < 4; ++q)
                if (v[q] > bv || (v[q] == bv && g[q] < bg)) { bv = v[q]; bg = g[q]; }
#pragma unroll
            for (int off = 32; off > 0; off >>= 1) {
                double ov = __shfl_xor(bv, off);
                int og = __shfl_xor(bg, off);
                if (ov > bv || (ov == bv && og < bg)) { bv = ov; bg = og; }
            }
            if (t == 0) orow[r] = bg;
#pragma unroll
            for (int q = 0; q < 4; ++q)
                if (g[q] == bg) v[q] = -1e300;
        }
    }
}

// ---------------------------------------------------------------------------
// fp64 NN GEMM: out(rows x 512) = A(rows x 512) @ W(512x512 fp32) [+ res]
// 128x64 tile, 256 threads, 8x4 microtile, BK=16. Per-element k-order
// identical to the verified rounds -> bit-exact trajectory. This round:
// inner-loop LDS reads vectorized as double2 (ds_read_b128; As/Bs strides
// 130/66 doubles are provably 16B-aligned) — same elements, same FMA order.
// ---------------------------------------------------------------------------
template <bool RES>
__global__ __launch_bounds__(256) void gemm_f64_k(const double* __restrict__ A,
                                                  const float* __restrict__ W,
                                                  const double* __restrict__ res,
                                                  double* __restrict__ out) {
    __shared__ double As[16][130];
    __shared__ double Bs[16][66];
    const int tx = threadIdx.x, ty = threadIdx.y;   // 16 x 16
    const int t = ty * 16 + tx;
    const int lk = t & 15, lr = t >> 4;
    const int wc = t & 63, wk = t >> 6;
    const int row0 = blockIdx.y * 128, col0 = blockIdx.x * 64;
    double acc[8][4] = {};
    for (int k0 = 0; k0 < C_; k0 += 16) {
#pragma unroll
        for (int p = 0; p < 8; ++p) {
            int r = lr + 16 * p;
            As[lk][r] = A[(size_t)(row0 + r) * C_ + k0 + lk];
        }
#pragma unroll
        for (int p = 0; p < 4; ++p)
            Bs[wk + 4 * p][wc] = (double)W[(size_t)(k0 + wk + 4 * p) * C_ + col0 + wc];
        __syncthreads();
#pragma unroll
        for (int kk = 0; kk < 16; ++kk) {
            const double2* ap = (const double2*)&As[kk][ty * 8];
            const double2* bp = (const double2*)&Bs[kk][tx * 4];
            double2 av0 = ap[0], av1 = ap[1], av2 = ap[2], av3 = ap[3];
            double2 bv0 = bp[0], bv1 = bp[1];
            double a[8], b[4];
            a[0] = av0.x; a[1] = av0.y; a[2] = av1.x; a[3] = av1.y;
            a[4] = av2.x; a[5] = av2.y; a[6] = av3.x; a[7] = av3.y;
            b[0] = bv0.x; b[1] = bv0.y; b[2] = bv1.x; b[3] = bv1.y;
#pragma unroll
            for (int i = 0; i < 8; ++i)
#pragma unroll
                for (int j = 0; j < 4; ++j) acc[i][j] += a[i] * b[j];
        }
        __syncthreads();
    }
#pragma unroll
    for (int i = 0; i < 8; ++i) {
        size_t r = row0 + ty * 8 + i;
#pragma unroll
        for (int j = 0; j < 4; ++j) {
            size_t o = r * C_ + col0 + tx * 4 + j;
            double v = acc[i][j];
            if (RES) v += res[o];
            out[o] = v;
        }
    }
}

// ---------------------------------------------------------------------------
// per-row 16-way cross attention, IN-PLACE on q, batched over B*N rows.
// XCD swizzle (same remap as select) for Kb/Vb gather L2 locality.
// Per-wave shfl logit reduce + 16-lane shfl softmax (round-4, passed).
// ---------------------------------------------------------------------------
__global__ __launch_bounds__(256) void attn_k(double* qo,
                                              const float* __restrict__ Kb,
                                              const float* __restrict__ Vb,
                                              const int* __restrict__ idx) {
    const int row = ((blockIdx.x & 7) << 10) | (blockIdx.x >> 3);   // batch->XCD
    const int bat = row >> 10;
    const int t = threadIdx.x;
    const int lane = t & 63, w = t >> 6;
    __shared__ int sidx[KNN_];
    __shared__ double wred[4][KNN_];
    __shared__ double sw[KNN_];
    if (t < KNN_) sidx[t] = idx[(size_t)row * KNN_ + t];
    __syncthreads();
    double q0 = qo[(size_t)row * C_ + t];
    double q1 = qo[(size_t)row * C_ + t + 256];
    double p[KNN_];
#pragma unroll
    for (int j = 0; j < KNN_; ++j) {
        const float* kr = Kb + ((size_t)bat * M_ + sidx[j]) * C_;
        p[j] = q0 * (double)kr[t] + q1 * (double)kr[t + 256];
    }
#pragma unroll
    for (int j = 0; j < KNN_; ++j) {
        double s = p[j];
#pragma unroll
        for (int o = 32; o > 0; o >>= 1) s += __shfl_down(s, o);
        if (lane == 0) wred[w][j] = s;
    }
    __syncthreads();
    if (t < KNN_) {
        const double scale = 1.0 / sqrt((double)C_);
        double l = (wred[0][t] + wred[1][t] + wred[2][t] + wred[3][t]) * scale;
        double mx = l;
#pragma unroll
        for (int o = 8; o > 0; o >>= 1) {
            double om = __shfl_xor(mx, o, 16);
            mx = om > mx ? om : mx;
        }
        double e = exp(l - mx);
        double ssum = e;
#pragma unroll
        for (int o = 8; o > 0; o >>= 1) ssum += __shfl_xor(ssum, o, 16);
        sw[t] = e * (1.0 / ssum);
    }
    __syncthreads();
    double o0 = 0.0, o1 = 0.0;
#pragma unroll
    for (int j = 0; j < KNN_; ++j) {
        const float* vr = Vb + ((size_t)bat * M_ + sidx[j]) * C_;
        double wgt = sw[j];
        o0 += wgt * (double)vr[t];
        o1 += wgt * (double)vr[t + 256];
    }
    qo[(size_t)row * C_ + t] = o0;
    qo[(size_t)row * C_ + t + 256] = o1;
}

// ---------------------------------------------------------------------------
extern "C" void kernel_launch(void* const* d_in, const int* in_sizes, int n_in,
                              void* d_out, int out_size, void* d_ws, size_t ws_size,
                              hipStream_t stream) {
    const float* slots_in = (const float*)d_in[0];
    const float* reflist  = (const float*)d_in[1];
    const float* Wq = (const float*)d_in[2];
    const float* Wk = (const float*)d_in[3];
    const float* Wv = (const float*)d_in[4];
    const float* Wo = (const float*)d_in[5];
    // reference uses only the LAST ref in ref_pt_list
    const float* ref = reflist + ((size_t)in_sizes[1] - (size_t)B_ * M_ * C_);
    float* out = (float*)d_out;

    const size_t NR = (size_t)B_ * N_;   // 8192 slot rows
    const size_t MR = (size_t)B_ * M_;   // 32768 ref rows

    // workspace carve — all-batch layout, ~389 MB of 512 MiB
    char* w = (char*)d_ws;
    double* slots_d = (double*)w;             w += NR * C_ * 8;            //  33.5 MB
    float*  corr    = (float*)w;              w += NR * M_ * 4;            // 134.2 MB
    float*  Kb      = (float*)w;              w += MR * C_ * 4;            //  67.1 MB
    float*  Vb      = (float*)w;              w += MR * C_ * 4;            //  67.1 MB
    __hip_bfloat16* Bhi = (__hip_bfloat16*)w; w += MR * C_ * 2;            //  33.5 MB
    __hip_bfloat16* Blo = (__hip_bfloat16*)w; w += MR * C_ * 2;            //  33.5 MB
    __hip_bfloat16* Ahi = (__hip_bfloat16*)w; w += NR * C_ * 2;            //   8.4 MB
    __hip_bfloat16* Alo = (__hip_bfloat16*)w; w += NR * C_ * 2;            //   8.4 MB
    __hip_bfloat16* Wkh = (__hip_bfloat16*)w; w += (size_t)C_ * C_ * 2;
    __hip_bfloat16* Wkl = (__hip_bfloat16*)w; w += (size_t)C_ * C_ * 2;
    __hip_bfloat16* Wvh = (__hip_bfloat16*)w; w += (size_t)C_ * C_ * 2;
    __hip_bfloat16* Wvl = (__hip_bfloat16*)w; w += (size_t)C_ * C_ * 2;
    double* inv_ns  = (double*)w;             w += NR * 8;
    double* inv_nr  = (double*)w;             w += MR * 8;
    double* rn      = (double*)w;             w += MR * 8;
    int*    idxb    = (int*)w;                w += NR * KNN_ * 4;
    double* qbuf    = (double*)corr;  // corr dead after select; fp64 q = 33.5 MB

    // ---- setup (once) ----
    f32_to_f64_k<<<4096, 256, 0, stream>>>(slots_in, slots_d, (int)(NR * C_));
    norm_split_ref_k<<<(int)MR, 64, 0, stream>>>(ref, inv_nr, rn, Bhi, Blo);
    split_w_k<<<512, 256, 0, stream>>>(Wk, Wv, Wkh, Wkl, Wvh, Wvl);
    // Kb = rn .* (ref_n @ Wk), Vb analogous — full 3-MFMA split (trajectory-
    // critical precision, round-5 lesson), rows = 32768
    mfma_nt_k<true><<<dim3(C_ / 128, MR / 128, 1), 256, 0, stream>>>(
        Bhi, Blo, 0, Wkh, Wkl, 0, Kb, 0, C_, rn);
    mfma_nt_k<true><<<dim3(C_ / 128, MR / 128, 1), 256, 0, stream>>>(
        Bhi, Blo, 0, Wvh, Wvl, 0, Vb, 0, C_, rn);

    for (int it = 0; it < ITERS_; ++it) {
        norm_split_slots_k<<<(int)NR, 64, 0, stream>>>(slots_d, inv_ns, Ahi, Alo);
        // corr (fp32, 2-MFMA split — selection-protected precision), z = batch
        mfma_nt_k<false><<<dim3(M_ / 128, N_ / 128, B_), 256, 0, stream>>>(
            Ahi, Alo, (size_t)N_ * C_, Bhi, Blo, (size_t)M_ * C_,
            corr, (size_t)N_ * M_, M_, nullptr);
        select_rerank_k<<<(int)NR, 256, 0, stream>>>(corr, slots_d, ref, inv_ns, inv_nr, idxb);
        // q = slots @ Wq (fp64, into corr-aliased qbuf)
        gemm_f64_k<false><<<dim3(C_ / 64, NR / 128), dim3(16, 16), 0, stream>>>(
            slots_d, Wq, (const double*)nullptr, qbuf);
        attn_k<<<(int)NR, 256, 0, stream>>>(qbuf, Kb, Vb, idxb);
        // slots += attnout @ Wo (fp64)
        gemm_f64_k<true><<<dim3(C_ / 64, NR / 128), dim3(16, 16), 0, stream>>>(
            qbuf, Wo, slots_d, slots_d);
    }

    f64_to_f32_k<<<4096, 256, 0, stream>>>(slots_d, out, (int)(NR * C_));
}